// Round 5
// baseline (332.911 us; speedup 1.0000x reference)
//
#include <hip/hip_runtime.h>
#include <stdint.h>

// Problem constants (fixed shapes from setup_inputs)
#define S_LEN  2048
#define B_DIM  8
#define E_DIM  1024
#define BE     (B_DIM * E_DIM)      // 8192  (one time-step's elements)
#define M_ROWS (S_LEN * B_DIM)      // 16384 (GEMM M)
#define NCHUNK 128
#define CLEN   (S_LEN / NCHUNK)     // 16
#define P_PER_T (BE / 2)            // 4096 channel-pairs per time-step

typedef __attribute__((ext_vector_type(8))) short bf16x8;  // 8 bf16 (4 VGPRs)
typedef __attribute__((ext_vector_type(4))) float f32x4;

__device__ __forceinline__ unsigned short f2bf(float f) {
    // round-to-nearest-even f32 -> bf16 (no NaN inputs expected)
    unsigned int u = __float_as_uint(f);
    u += 0x7FFFu + ((u >> 16) & 1u);
    return (unsigned short)(u >> 16);
}
__device__ __forceinline__ float bf_lo(unsigned int u) {
    return __uint_as_float(u << 16);
}
__device__ __forceinline__ float bf_hi(unsigned int u) {
    return __uint_as_float(u & 0xFFFF0000u);
}

// ---------------------------------------------------------------------------
// 1. token-shift mix: xk = mk*x + (1-mk)*x_prev, xv likewise; output bf16.
//    8 elements/thread: 2x float4 loads, 1x ushort8 (16B) store per output.
// ---------------------------------------------------------------------------
__global__ __launch_bounds__(256) void mix_kernel(
    const float* __restrict__ x, const float* __restrict__ tmrkv,
    unsigned short* __restrict__ xk, unsigned short* __restrict__ xv)
{
    int i = blockIdx.x * 256 + threadIdx.x;           // 8-elem group index
    const float4* x4 = (const float4*)x;
    float4 xc[2], xp[2];
    xc[0] = x4[2 * i];
    xc[1] = x4[2 * i + 1];
    if (i >= BE / 8) {
        xp[0] = x4[2 * i - BE / 4];
        xp[1] = x4[2 * i + 1 - BE / 4];
    } else {
        xp[0] = make_float4(0.f, 0.f, 0.f, 0.f);
        xp[1] = make_float4(0.f, 0.f, 0.f, 0.f);
    }
    int e4 = (2 * i) & (E_DIM / 4 - 1);
    ushort4 ok[2], ov[2];
    #pragma unroll
    for (int h = 0; h < 2; ++h) {
        float4 mk = ((const float4*)(tmrkv + E_DIM))[e4 + h];
        float4 mv = ((const float4*)(tmrkv + 2 * E_DIM))[e4 + h];
        ok[h].x = f2bf(mk.x * xc[h].x + (1.f - mk.x) * xp[h].x);
        ok[h].y = f2bf(mk.y * xc[h].y + (1.f - mk.y) * xp[h].y);
        ok[h].z = f2bf(mk.z * xc[h].z + (1.f - mk.z) * xp[h].z);
        ok[h].w = f2bf(mk.w * xc[h].w + (1.f - mk.w) * xp[h].w);
        ov[h].x = f2bf(mv.x * xc[h].x + (1.f - mv.x) * xp[h].x);
        ov[h].y = f2bf(mv.y * xc[h].y + (1.f - mv.y) * xp[h].y);
        ov[h].z = f2bf(mv.z * xc[h].z + (1.f - mv.z) * xp[h].z);
        ov[h].w = f2bf(mv.w * xc[h].w + (1.f - mv.w) * xp[h].w);
    }
    ((ushort4*)xk)[2 * i]     = ok[0];
    ((ushort4*)xk)[2 * i + 1] = ok[1];
    ((ushort4*)xv)[2 * i]     = ov[0];
    ((ushort4*)xv)[2 * i + 1] = ov[1];
}

// ---------------------------------------------------------------------------
// 2. cast + transpose weights f32[K][N] -> bf16[N][K]; 3 matrices via grid z
// ---------------------------------------------------------------------------
__global__ __launch_bounds__(256) void cast_transpose_k(
    const float* __restrict__ w0, const float* __restrict__ w1,
    const float* __restrict__ w2,
    unsigned short* __restrict__ o0, unsigned short* __restrict__ o1,
    unsigned short* __restrict__ o2)
{
    const float* in = blockIdx.z == 0 ? w0 : (blockIdx.z == 1 ? w1 : w2);
    unsigned short* out = blockIdx.z == 0 ? o0 : (blockIdx.z == 1 ? o1 : o2);
    __shared__ float tile[32][33];
    int bx = blockIdx.x * 32, by = blockIdx.y * 32;
    int tx = threadIdx.x, ty = threadIdx.y;           // block (32, 8)
    #pragma unroll
    for (int i = 0; i < 32; i += 8)
        tile[ty + i][tx] = in[(size_t)(by + ty + i) * E_DIM + bx + tx];
    __syncthreads();
    #pragma unroll
    for (int i = 0; i < 32; i += 8)
        out[(size_t)(bx + ty + i) * E_DIM + by + tx] = f2bf(tile[tx][ty + i]);
}

// ---------------------------------------------------------------------------
// 3. bf16 MFMA GEMM: C[M][N] = A[M][K] bf16 @ (BT[N][K] bf16)^T
//    128x128 tile, BK=64 (128B rows), XOR-8 chunk swizzle (conflict-free,
//    verified 4.19M -> 0). N-tile is the FAST grid dim (blockIdx.x) so 8
//    consecutive blocks share one A-tile -> A re-reads stay L2-warm.
// ---------------------------------------------------------------------------
#define BM 128
#define BN 128
#define BK 64

template <typename OutT>
__device__ __forceinline__ void gemm_body(
    const unsigned short* __restrict__ A,
    const unsigned short* __restrict__ BT,
    OutT* __restrict__ C, int M, int N, int K)
{
    __shared__ __align__(16) unsigned short As[BM * BK];  // 16 KiB, 128B rows
    __shared__ __align__(16) unsigned short Bs[BN * BK];  // 16 KiB
    const int tid  = threadIdx.x;
    const int wave = tid >> 6, lane = tid & 63;
    const int bm = blockIdx.y * BM, bn = blockIdx.x * BN; // x = N (fast)
    const int wr = (wave >> 1) * 64, wc = (wave & 1) * 64; // wave's 64x64 region
    const int lrow = lane & 15, lq = lane >> 4;

    f32x4 acc[4][4];
    #pragma unroll
    for (int i = 0; i < 4; ++i)
        #pragma unroll
        for (int j = 0; j < 4; ++j)
            acc[i][j] = (f32x4){0.f, 0.f, 0.f, 0.f};

    const int nk = K / BK;
    for (int kt = 0; kt < nk; ++kt) {
        __syncthreads();                               // prev reads done
        const int kk = kt * BK;
        // stage A and B tiles: 1024 chunks of 16B each per matrix.
        // lds chunk idx = s*256 + wave*64 + lane (HW: wave base + lane*16).
        // row = idx>>3, lds col c' = idx&7, global chunk gc = c' ^ (row&7).
        #pragma unroll
        for (int s = 0; s < 4; ++s) {
            int idx = s * 256 + wave * 64 + lane;
            int r   = idx >> 3;
            int gc  = (idx & 7) ^ (r & 7);
            const char* ga = (const char*)(A  + (size_t)(bm + r) * K + kk) + gc * 16;
            const char* gb = (const char*)(BT + (size_t)(bn + r) * K + kk) + gc * 16;
            char* la = (char*)As + s * 4096 + wave * 1024;   // wave-uniform
            char* lb = (char*)Bs + s * 4096 + wave * 1024;
            __builtin_amdgcn_global_load_lds(
                (const __attribute__((address_space(1))) unsigned int*)ga,
                (__attribute__((address_space(3))) unsigned int*)la, 16, 0, 0);
            __builtin_amdgcn_global_load_lds(
                (const __attribute__((address_space(1))) unsigned int*)gb,
                (__attribute__((address_space(3))) unsigned int*)lb, 16, 0, 0);
        }
        __syncthreads();                               // drains vmcnt + barrier

        #pragma unroll
        for (int h = 0; h < 2; ++h) {                  // two K=32 halves
            bf16x8 af[4], bf[4];
            #pragma unroll
            for (int i = 0; i < 4; ++i) {
                int R = wr + i * 16 + lrow;
                af[i] = *(const bf16x8*)&As[R * BK + (((h << 2) | lq) ^ (R & 7)) * 8];
            }
            #pragma unroll
            for (int j = 0; j < 4; ++j) {
                int R = wc + j * 16 + lrow;
                bf[j] = *(const bf16x8*)&Bs[R * BK + (((h << 2) | lq) ^ (R & 7)) * 8];
            }
            #pragma unroll
            for (int i = 0; i < 4; ++i)
                #pragma unroll
                for (int j = 0; j < 4; ++j)
                    acc[i][j] = __builtin_amdgcn_mfma_f32_16x16x32_bf16(
                        af[i], bf[j], acc[i][j], 0, 0, 0);
        }
    }

    // epilogue: D[row=(lane>>4)*4+r][col=lane&15] per 16x16 subtile
    #pragma unroll
    for (int i = 0; i < 4; ++i)
        #pragma unroll
        for (int j = 0; j < 4; ++j)
            #pragma unroll
            for (int r = 0; r < 4; ++r) {
                int row = bm + wr + i * 16 + lq * 4 + r;
                int col = bn + wc + j * 16 + lrow;
                if constexpr (sizeof(OutT) == 2)
                    C[(size_t)row * N + col] = f2bf(acc[i][j][r]);
                else
                    C[(size_t)row * N + col] = acc[i][j][r];
            }
}

__global__ __launch_bounds__(256) void gemm_kv(
    const unsigned short* __restrict__ A0, const unsigned short* __restrict__ B0,
    unsigned short* __restrict__ C0,
    const unsigned short* __restrict__ A1, const unsigned short* __restrict__ B1,
    unsigned short* __restrict__ C1, int M, int N, int K)
{
    if (blockIdx.z == 0) gemm_body<unsigned short>(A0, B0, C0, M, N, K);
    else                 gemm_body<unsigned short>(A1, B1, C1, M, N, K);
}

__global__ __launch_bounds__(256) void gemm_out(
    const unsigned short* __restrict__ A, const unsigned short* __restrict__ BT,
    float* __restrict__ C, int M, int N, int K)
{
    gemm_body<float>(A, BT, C, M, N, K);
}

// ---------------------------------------------------------------------------
// 4. WKV associative scan, chunked 3-pass, NCHUNK=128, 2 channels/thread.
//    Single-exp combine: pn = max(pw,kt) means one of e1,e2 is exp(0)=1,
//    so em = exp(-|kt-pw|) + 2 selects replaces 2 transcendentals.
// ---------------------------------------------------------------------------
__device__ __forceinline__ void wkv_step(float& a, float& b, float& p,
                                         float kt, float vt, float w)
{
    float pw = p + w;
    float d  = kt - pw;
    float em = __expf(-fabsf(d));
    bool  c  = d > 0.f;
    float e1 = c ? em : 1.f;
    float e2 = c ? 1.f : em;
    a = a * e1 + vt * e2;
    b = b * e1 + e2;
    p = fmaxf(pw, kt);
}

// combine summaries: left(la,lb,lp) then right(ra,rb,rp) with right-span
// accumulated decay Wr. Identity-left (lp=-inf) handled naturally (em->0).
__device__ __forceinline__ void wkv_combine(float& la, float& lb, float& lp,
                                            float ra, float rb, float rp,
                                            float Wr)
{
    float pw = lp + Wr;
    float d  = rp - pw;
    float em = __expf(-fabsf(d));
    bool  c  = d > 0.f;
    float e1 = c ? em : 1.f;
    float e2 = c ? 1.f : em;
    la = la * e1 + ra * e2;
    lb = lb * e1 + rb * e2;
    lp = fmaxf(pw, rp);
}

__global__ __launch_bounds__(256) void scan_pass1(
    const unsigned int* __restrict__ k2, const unsigned int* __restrict__ v2,
    const float* __restrict__ tdec,
    float2* __restrict__ sA, float2* __restrict__ sB, float2* __restrict__ sP)
{
    int g  = blockIdx.x * 256 + threadIdx.x;   // g = c*P_PER_T + pr
    int pr = g & (P_PER_T - 1);
    int c  = g >> 12;
    float2 w2 = ((const float2*)tdec)[pr & (E_DIM / 2 - 1)];
    size_t idx = (size_t)c * CLEN * P_PER_T + pr;
    unsigned int ku = k2[idx], vu = v2[idx];
    float a0 = bf_lo(vu), b0 = 1.f, p0 = bf_lo(ku);
    float a1 = bf_hi(vu), b1 = 1.f, p1 = bf_hi(ku);
    #pragma unroll
    for (int j = 1; j < CLEN; ++j) {
        idx += P_PER_T;
        ku = k2[idx]; vu = v2[idx];
        wkv_step(a0, b0, p0, bf_lo(ku), bf_lo(vu), w2.x);
        wkv_step(a1, b1, p1, bf_hi(ku), bf_hi(vu), w2.y);
    }
    sA[g] = make_float2(a0, a1);
    sB[g] = make_float2(b0, b1);
    sP[g] = make_float2(p0, p1);
}

// Cross-chunk exclusive scan: block = 32 channels x 128 chunks; each lane
// owns a chunk-pair: serial pair-combine -> 64-lane shuffle scan -> fix-up.
__global__ __launch_bounds__(256) void scan_pass2(
    const float* __restrict__ tdec,
    float* __restrict__ sA, float* __restrict__ sB, float* __restrict__ sP)
{
    __shared__ float tA[32 * 130], tB[32 * 130], tP[32 * 130];
    const int t   = threadIdx.x;
    const int ch0 = blockIdx.x * 32;
    const int chl = t & 31;
    const int cq  = t >> 5;                    // 0..7
    #pragma unroll 4
    for (int cc = 0; cc < 16; ++cc) {
        int c = cq * 16 + cc;
        int idx = c * BE + ch0 + chl;
        tA[chl * 130 + c] = sA[idx];
        tB[chl * 130 + c] = sB[idx];
        tP[chl * 130 + c] = sP[idx];
    }
    __syncthreads();
    const int lane = t & 63, wave = t >> 6;    // 4 waves x 8 channels each
    for (int i = 0; i < 8; ++i) {
        int ch = wave * 8 + i;                 // local channel 0..31
        float w  = tdec[(ch0 + ch) & (E_DIM - 1)];
        float Lw = (float)CLEN * w;            // one chunk's total decay
        int c0 = 2 * lane, c1 = 2 * lane + 1;
        float a0 = tA[ch * 130 + c0], b0 = tB[ch * 130 + c0], p0 = tP[ch * 130 + c0];
        float a1 = tA[ch * 130 + c1], b1 = tB[ch * 130 + c1], p1 = tP[ch * 130 + c1];
        // pair summary (span 2*Lw)
        float a = a0, b = b0, p = p0;
        wkv_combine(a, b, p, a1, b1, p1, Lw);
        float W = 2.f * Lw;
        // inclusive 64-lane scan of pair summaries
        #pragma unroll
        for (int d = 1; d < 64; d <<= 1) {
            float a_l = __shfl_up(a, d);
            float b_l = __shfl_up(b, d);
            float p_l = __shfl_up(p, d);
            float W_l = __shfl_up(W, d);
            if (lane >= d) {
                float na = a_l, nb = b_l, np = p_l;
                wkv_combine(na, nb, np, a, b, p, W);
                a = na; b = nb; p = np;
                W = W_l + W;
            }
        }
        // exclusive pair prefix
        float ea = __shfl_up(a, 1);
        float eb = __shfl_up(b, 1);
        float ep = __shfl_up(p, 1);
        if (lane == 0) { ea = 0.f; eb = 0.f; ep = -__builtin_inff(); }
        // chunk c0 prefix = pair prefix; chunk c1 prefix = prefix (+) chunk c0
        tA[ch * 130 + c0] = ea;
        tB[ch * 130 + c0] = eb;
        tP[ch * 130 + c0] = ep;
        wkv_combine(ea, eb, ep, a0, b0, p0, Lw);
        tA[ch * 130 + c1] = ea;
        tB[ch * 130 + c1] = eb;
        tP[ch * 130 + c1] = ep;
    }
    __syncthreads();
    #pragma unroll 4
    for (int cc = 0; cc < 16; ++cc) {
        int c = cq * 16 + cc;
        int idx = c * BE + ch0 + chl;
        sA[idx] = tA[chl * 130 + c];
        sB[idx] = tB[chl * 130 + c];
        sP[idx] = tP[chl * 130 + c];
    }
}

__global__ __launch_bounds__(256) void scan_pass3(
    const unsigned int* __restrict__ k2, const unsigned int* __restrict__ v2,
    const float* __restrict__ tdec, const float* __restrict__ tfir,
    const float2* __restrict__ sA, const float2* __restrict__ sB,
    const float2* __restrict__ sP, unsigned int* __restrict__ rwkv2)
{
    int g  = blockIdx.x * 256 + threadIdx.x;   // pair index
    int pr = g & (P_PER_T - 1);
    int c  = g >> 12;
    int e2i = pr & (E_DIM / 2 - 1);
    float2 w2 = ((const float2*)tdec)[e2i];
    float2 f2 = ((const float2*)tfir)[e2i];
    float u0 = f2.x + w2.x, u1 = f2.y + w2.y;  // time_first + time_decay
    float2 av = sA[g], bv = sB[g], pv = sP[g]; // carry-in (excl prefix)
    float a0 = av.x, b0 = bv.x, p0 = pv.x;
    float a1 = av.y, b1 = bv.y, p1 = pv.y;
    size_t idx = (size_t)c * CLEN * P_PER_T + pr;
    #pragma unroll
    for (int j = 0; j < CLEN; ++j) {
        unsigned int ku = k2[idx], vu = v2[idx];
        float kt0 = bf_lo(ku), vt0 = bf_lo(vu);
        float kt1 = bf_hi(ku), vt1 = bf_hi(vu);
        wkv_step(a0, b0, p0, kt0, vt0, w2.x);
        wkv_step(a1, b1, p1, kt1, vt1, w2.y);
        // bonus-mix output: exp_mix_frac(p, k+u+w, a, b, v, 1) — single exp
        float kb0 = kt0 + u0, kb1 = kt1 + u1;
        float d0 = kb0 - p0, d1 = kb1 - p1;
        float m0 = __expf(-fabsf(d0)), m1 = __expf(-fabsf(d1));
        bool  c0 = d0 > 0.f, c1 = d1 > 0.f;
        float f10 = c0 ? m0 : 1.f, f20 = c0 ? 1.f : m0;
        float f11 = c1 ? m1 : 1.f, f21 = c1 ? 1.f : m1;
        float n0 = a0 * f10 + vt0 * f20, de0 = b0 * f10 + f20;
        float n1 = a1 * f11 + vt1 * f21, de1 = b1 * f11 + f21;
        float r0 = n0 * __builtin_amdgcn_rcpf(de0);
        float r1 = n1 * __builtin_amdgcn_rcpf(de1);
        rwkv2[idx] = (unsigned int)f2bf(r0) | ((unsigned int)f2bf(r1) << 16);
        idx += P_PER_T;
    }
}

// ---------------------------------------------------------------------------
extern "C" void kernel_launch(void* const* d_in, const int* in_sizes, int n_in,
                              void* d_out, int out_size, void* d_ws, size_t ws_size,
                              hipStream_t stream)
{
    const float* x     = (const float*)d_in[0];
    const float* tmrkv = (const float*)d_in[1];
    const float* Wk    = (const float*)d_in[2];
    const float* Wv    = (const float*)d_in[3];
    const float* tdec  = (const float*)d_in[4];
    const float* tfir  = (const float*)d_in[5];
    const float* Wout  = (const float*)d_in[6];
    float* out = (float*)d_out;

    // workspace layout (all bf16): xk | xv | k | v | WkT | WvT | WoutT
    // reuse: rwkv -> xk space (dead after gemm_kv); scan scratch -> xv space
    char* ws = (char*)d_ws;
    const size_t SZ_BF = (size_t)M_ROWS * E_DIM * 2;   // 32 MiB
    unsigned short* xk   = (unsigned short*)(ws);
    unsigned short* xv   = (unsigned short*)(ws + SZ_BF);
    unsigned short* kbuf = (unsigned short*)(ws + 2 * SZ_BF);
    unsigned short* vbuf = (unsigned short*)(ws + 3 * SZ_BF);
    unsigned short* WkT  = (unsigned short*)(ws + 4 * SZ_BF);
    unsigned short* WvT  = WkT + (size_t)E_DIM * E_DIM;
    unsigned short* WoutT= WvT + (size_t)E_DIM * E_DIM;
    float* sA = (float*)xv;                    // 4 MiB each, xv dead by then
    float* sB = sA + (size_t)NCHUNK * BE;
    float* sP = sB + (size_t)NCHUNK * BE;
    unsigned short* rwkv = xk;                 // xk dead after gemm_kv

    // 1. mix (reads x; writes xk, xv bf16)
    mix_kernel<<<(M_ROWS * E_DIM / 8) / 256, 256, 0, stream>>>(x, tmrkv, xk, xv);

    // 2. weight casts (f32 [K][N] -> bf16 [N][K]), one launch for all three
    dim3 tb(32, 8), tg(E_DIM / 32, E_DIM / 32, 3);
    cast_transpose_k<<<tg, tb, 0, stream>>>(Wk, Wv, Wout, WkT, WvT, WoutT);

    // 3. k = xk @ Wk, v = xv @ Wv in ONE dispatch (bf16 out); N fast dim
    dim3 gkv(E_DIM / BN, M_ROWS / BM, 2);
    gemm_kv<<<gkv, 256, 0, stream>>>(xk, WkT, kbuf, xv, WvT, vbuf,
                                     M_ROWS, E_DIM, E_DIM);

    // 4. chunked associative scan -> rwkv bf16 (128 chunks, 2 ch/thread)
    scan_pass1<<<(NCHUNK * P_PER_T) / 256, 256, 0, stream>>>(
        (const unsigned int*)kbuf, (const unsigned int*)vbuf, tdec,
        (float2*)sA, (float2*)sB, (float2*)sP);
    scan_pass2<<<BE / 32, 256, 0, stream>>>(tdec, sA, sB, sP);
    scan_pass3<<<(NCHUNK * P_PER_T) / 256, 256, 0, stream>>>(
        (const unsigned int*)kbuf, (const unsigned int*)vbuf, tdec, tfir,
        (const float2*)sA, (const float2*)sB, (const float2*)sP,
        (unsigned int*)rwkv);

    // 5. out = rwkv @ Wout  (f32 out); N fast dim
    dim3 gg(E_DIM / BN, M_ROWS / BM);
    gemm_out<<<gg, 256, 0, stream>>>(rwkv, WoutT, out, M_ROWS, E_DIM, E_DIM);
}